// Round 5
// baseline (382.033 us; speedup 1.0000x reference)
//
#include <hip/hip_runtime.h>
#include <hip/hip_fp16.h>

typedef short short8 __attribute__((ext_vector_type(8)));
typedef int int4v __attribute__((ext_vector_type(4)));
typedef unsigned int uint4v __attribute__((ext_vector_type(4)));
typedef float f32x4 __attribute__((ext_vector_type(4)));

constexpr int Hdim = 128;
constexpr int Steps = 27;
constexpr int GSTR = 772;   // g_lds row stride (floats): 4*772%32=16 -> spill quads 2-way

__device__ __forceinline__ short f2bf(float f) {
  unsigned u = __float_as_uint(f);
  u += 0x7FFFu + ((u >> 16) & 1u);  // RNE
  return (short)(u >> 16);
}
__device__ __forceinline__ float bf2f(short s) {
  return __uint_as_float(((unsigned)(unsigned short)s) << 16);
}
__device__ __forceinline__ unsigned packbf(float v) {
  unsigned short hi = (unsigned short)f2bf(v);
  unsigned short lo = (unsigned short)f2bf(v - bf2f((short)hi));
  return ((unsigned)hi << 16) | (unsigned)lo;
}
__device__ __forceinline__ float sigmoidf_(float x) { return 1.0f / (1.0f + __expf(-x)); }
__device__ __forceinline__ float tanh_(float x) { return 1.0f - 2.0f / (__expf(2.0f * x) + 1.0f); }

// XOR block swizzles: make 16-row x 4-quad b128 LDS access exactly 2-way (free)
__device__ __forceinline__ int aswz(int row, int k) {   // shorts, K=256, stride 256
  return row * 256 + ((((k >> 3) ^ row) & 7) << 3) + (k & ~7 & ~56) + (k & 7) - (k & 56) + ((k >> 3) & ~7) * 8;
}
// (simplified correct form below; keep one canonical implementation)
__device__ __forceinline__ int aidx(int row, int k) {   // shorts, K=256, stride 256
  int blk = k >> 3;
  return row * 256 + (((blk ^ (row & 7)) & 31) << 3) + (k & 7);
}
__device__ __forceinline__ int pidx(int row, int n) {   // u32, K=128, stride 128
  int blk = n >> 2;
  return row * 128 + (((blk ^ (row & 7)) & 31) << 2) + (n & 3);
}
__device__ __forceinline__ int xidx(int row, int k) {   // shorts, K=64, stride 64
  int blk = k >> 3;
  return row * 64 + (((blk ^ (row & 7)) & 7) << 3) + (k & 7);
}

// load one MFMA B-fragment (bf16 hi) from an fp32 row-major matrix
__device__ __forceinline__ short8 ldfrag(const float* __restrict__ base, int rstride,
                                         int n0, int k0, int lane) {
  const float* p = base + (size_t)(n0 + (lane & 15)) * rstride + k0 + ((lane >> 4) << 3);
  f32x4 a = *(const f32x4*)p;
  f32x4 b = *(const f32x4*)(p + 4);
  short8 h;
  h[0] = f2bf(a.x); h[1] = f2bf(a.y); h[2] = f2bf(a.z); h[3] = f2bf(a.w);
  h[4] = f2bf(b.x); h[5] = f2bf(b.y); h[6] = f2bf(b.z); h[7] = f2bf(b.w);
  return h;
}
__device__ __forceinline__ void ldfrag2(const float* __restrict__ base, int rstride,
                                        int n0, int k0, int lane, short8& hi, short8& lo) {
  const float* p = base + (size_t)(n0 + (lane & 15)) * rstride + k0 + ((lane >> 4) << 3);
  f32x4 a = *(const f32x4*)p;
  f32x4 b = *(const f32x4*)(p + 4);
  float v[8] = {a.x, a.y, a.z, a.w, b.x, b.y, b.z, b.w};
#pragma unroll
  for (int j = 0; j < 8; ++j) {
    short h = f2bf(v[j]);
    hi[j] = h;
    lo[j] = f2bf(v[j] - bf2f(h));
  }
}

// ---- kernel 1: fused frontend MLP + xW precompute (all MFMA) ----
// block = 64 rows of the 12288-row hgrid; writes xWb[cls][bn][l][n] (fp16) =
//   hg[l] @ W_enc[cls][:,256:384]^T + (r+c<12 ? B_enc[cls] : 0)
__global__ __launch_bounds__(512, 1) void prelude(
    const float* __restrict__ x, const float* __restrict__ fc3_w, const float* __restrict__ fc3_b,
    const float* __restrict__ fc4_w, const float* __restrict__ fc4_b,
    const float* __restrict__ W_enc, const float* __restrict__ B_enc, __half* __restrict__ xWb) {
  const int t = threadIdx.x;
  const int lane = t & 63;
  const int wv = t >> 6;          // 0..7
  const int arow = lane & 15;
  const int quad = lane >> 4;
  const int row0 = blockIdx.x * 64;
  const int bn = row0 / 192;
  const int l0 = row0 % 192;

  __shared__ __attribute__((aligned(16))) short Axhi[64 * 64];
  __shared__ __attribute__((aligned(16))) short Axlo[64 * 64];
  __shared__ __attribute__((aligned(16))) unsigned h1pk[64 * 128];
  __shared__ int actf[64];

  // stage x (64 rows x 64) as bf16 hi/lo, swizzled
  {
    int r = t >> 3, c = (t & 7) * 8;
    const float* xp = x + (size_t)(row0 + r) * 64 + c;
    f32x4 a = *(const f32x4*)xp;
    f32x4 b = *(const f32x4*)(xp + 4);
    float v[8] = {a.x, a.y, a.z, a.w, b.x, b.y, b.z, b.w};
    short8 hi, lo;
#pragma unroll
    for (int j = 0; j < 8; ++j) {
      short h = f2bf(v[j]);
      hi[j] = h;
      lo[j] = f2bf(v[j] - bf2f(h));
    }
    *(short8*)&Axhi[xidx(r, c)] = hi;
    *(short8*)&Axlo[xidx(r, c)] = lo;
  }
  if (t < 64) {
    int ll = l0 + t;
    actf[t] = ((ll / 12) + (ll % 12)) < 12;
  }
  __syncthreads();

  // ---- fc3: [64x64] @ w3[128x64]^T, wave wv owns cols wv*16..+16 ----
  {
    float b3v = fc3_b[wv * 16 + (lane & 15)];
    short8 w3h[2], w3l[2];
#pragma unroll
    for (int ks = 0; ks < 2; ++ks) ldfrag2(fc3_w, 64, wv * 16, ks * 32, lane, w3h[ks], w3l[ks]);
    f32x4 acc[4] = {{0.f, 0.f, 0.f, 0.f}, {0.f, 0.f, 0.f, 0.f}, {0.f, 0.f, 0.f, 0.f}, {0.f, 0.f, 0.f, 0.f}};
#pragma unroll
    for (int mt = 0; mt < 4; ++mt)
#pragma unroll
      for (int ks = 0; ks < 2; ++ks) {
        short8 ah = *(const short8*)&Axhi[xidx(mt * 16 + arow, ks * 32 + quad * 8)];
        short8 al = *(const short8*)&Axlo[xidx(mt * 16 + arow, ks * 32 + quad * 8)];
        acc[mt] = __builtin_amdgcn_mfma_f32_16x16x32_bf16(ah, w3h[ks], acc[mt], 0, 0, 0);
        acc[mt] = __builtin_amdgcn_mfma_f32_16x16x32_bf16(al, w3h[ks], acc[mt], 0, 0, 0);
        acc[mt] = __builtin_amdgcn_mfma_f32_16x16x32_bf16(ah, w3l[ks], acc[mt], 0, 0, 0);
      }
#pragma unroll
    for (int mt = 0; mt < 4; ++mt)
#pragma unroll
      for (int r = 0; r < 4; ++r) {
        float v = fmaxf(acc[mt][r] + b3v, 0.f);
        h1pk[pidx(mt * 16 + quad * 4 + r, wv * 16 + (lane & 15))] = packbf(v);
      }
  }
  __syncthreads();

  // ---- fc4: h1[64x128] @ w4[128x128]^T -> hg (packed bf16 hi/lo, reuse h1pk) ----
  unsigned hgv[4][4];  // [mt][r] packed results
  {
    float b4v = fc4_b[wv * 16 + (lane & 15)];
    short8 w4h[4], w4l[4];
#pragma unroll
    for (int ks = 0; ks < 4; ++ks) ldfrag2(fc4_w, 128, wv * 16, ks * 32, lane, w4h[ks], w4l[ks]);
    f32x4 acc[4] = {{0.f, 0.f, 0.f, 0.f}, {0.f, 0.f, 0.f, 0.f}, {0.f, 0.f, 0.f, 0.f}, {0.f, 0.f, 0.f, 0.f}};
#pragma unroll
    for (int mt = 0; mt < 4; ++mt)
#pragma unroll
      for (int ks = 0; ks < 4; ++ks) {
        int k0 = ks * 32 + quad * 8;
        uint4v ua = *(const uint4v*)&h1pk[pidx(mt * 16 + arow, k0)];
        uint4v ub = *(const uint4v*)&h1pk[pidx(mt * 16 + arow, k0 + 4)];
        int4v hv, lv;
        hv.x = (int)((ua.x >> 16) | (ua.y & 0xFFFF0000u));
        hv.y = (int)((ua.z >> 16) | (ua.w & 0xFFFF0000u));
        hv.z = (int)((ub.x >> 16) | (ub.y & 0xFFFF0000u));
        hv.w = (int)((ub.z >> 16) | (ub.w & 0xFFFF0000u));
        lv.x = (int)((ua.x & 0xFFFFu) | (ua.y << 16));
        lv.y = (int)((ua.z & 0xFFFFu) | (ua.w << 16));
        lv.z = (int)((ub.x & 0xFFFFu) | (ub.w << 16 & 0u) | (ub.w << 16));  // placeholder fixed below
        lv.z = (int)((ub.x & 0xFFFFu) | (ub.y << 16));
        lv.w = (int)((ub.z & 0xFFFFu) | (ub.w << 16));
        short8 ah = __builtin_bit_cast(short8, hv);
        short8 al = __builtin_bit_cast(short8, lv);
        acc[mt] = __builtin_amdgcn_mfma_f32_16x16x32_bf16(ah, w4h[ks], acc[mt], 0, 0, 0);
        acc[mt] = __builtin_amdgcn_mfma_f32_16x16x32_bf16(al, w4h[ks], acc[mt], 0, 0, 0);
        acc[mt] = __builtin_amdgcn_mfma_f32_16x16x32_bf16(ah, w4l[ks], acc[mt], 0, 0, 0);
      }
#pragma unroll
    for (int mt = 0; mt < 4; ++mt)
#pragma unroll
      for (int r = 0; r < 4; ++r) hgv[mt][r] = packbf(acc[mt][r] + b4v);
  }
  __syncthreads();  // all h1pk reads done
#pragma unroll
  for (int mt = 0; mt < 4; ++mt)
#pragma unroll
    for (int r = 0; r < 4; ++r)
      h1pk[pidx(mt * 16 + quad * 4 + r, wv * 16 + (lane & 15))] = hgv[mt][r];
  __syncthreads();

  // ---- xW: hg[64x128] @ Wx[1536x128]^T (both classes), + cell bias, store fp16 ----
  short8 wx[12][4];
  float bv[12];
#pragma unroll
  for (int i = 0; i < 12; ++i) {
    int g = wv * 12 + i;
    int ci = g / 48, pt = g % 48;
    const float* wb = W_enc + (size_t)ci * 768 * 384;
#pragma unroll
    for (int ks = 0; ks < 4; ++ks) wx[i][ks] = ldfrag(wb, 384, pt * 16, 256 + ks * 32, lane);
    bv[i] = B_enc[ci * 768 + pt * 16 + (lane & 15)];
  }
  for (int mt = 0; mt < 4; ++mt) {
    short8 ah[4], al[4];
#pragma unroll
    for (int ks = 0; ks < 4; ++ks) {
      int k0 = ks * 32 + quad * 8;
      uint4v ua = *(const uint4v*)&h1pk[pidx(mt * 16 + arow, k0)];
      uint4v ub = *(const uint4v*)&h1pk[pidx(mt * 16 + arow, k0 + 4)];
      int4v hv, lv;
      hv.x = (int)((ua.x >> 16) | (ua.y & 0xFFFF0000u));
      hv.y = (int)((ua.z >> 16) | (ua.w & 0xFFFF0000u));
      hv.z = (int)((ub.x >> 16) | (ub.y & 0xFFFF0000u));
      hv.w = (int)((ub.z >> 16) | (ub.w & 0xFFFF0000u));
      lv.x = (int)((ua.x & 0xFFFFu) | (ua.y << 16));
      lv.y = (int)((ua.z & 0xFFFFu) | (ua.w << 16));
      lv.z = (int)((ub.x & 0xFFFFu) | (ub.y << 16));
      lv.w = (int)((ub.z & 0xFFFFu) | (ub.w << 16));
      ah[ks] = __builtin_bit_cast(short8, hv);
      al[ks] = __builtin_bit_cast(short8, lv);
    }
#pragma unroll
    for (int i = 0; i < 12; ++i) {
      f32x4 acc = {0.f, 0.f, 0.f, 0.f};
#pragma unroll
      for (int ks = 0; ks < 4; ++ks) {
        acc = __builtin_amdgcn_mfma_f32_16x16x32_bf16(ah[ks], wx[i][ks], acc, 0, 0, 0);
        acc = __builtin_amdgcn_mfma_f32_16x16x32_bf16(al[ks], wx[i][ks], acc, 0, 0, 0);
      }
      int g = wv * 12 + i;
      int ci = g / 48, pt = g % 48;
      int n = pt * 16 + (lane & 15);
      int lr0 = mt * 16 + quad * 4;
      __half* dst = xWb + (((size_t)ci * 64 + bn) * 192 + (l0 + lr0)) * 768 + n;
#pragma unroll
      for (int r = 0; r < 4; ++r) {
        float v = acc[r] + (actf[lr0 + r] ? bv[i] : 0.f);
        dst[(size_t)r * 768] = __float2half(v);
      }
    }
  }
}

// ---- kernel 2: recurrence. One self-contained 512-thread wg per (cls,bn). K=256. ----
__global__ __launch_bounds__(512, 1) void witran(
    const float* __restrict__ W_enc, const float* __restrict__ fc1_w, const float* __restrict__ fc1_b,
    const float* __restrict__ fc2_w, const float* __restrict__ fc2_b,
    const __half* __restrict__ xWb, float* __restrict__ out) {
  const int cls = blockIdx.x & 1;
  const int bn = blockIdx.x >> 1;
  const int t = threadIdx.x;
  const int lane = t & 63;
  const int wv = t >> 6;     // wave owns cols [wv*96, wv*96+96)
  const int arow = lane & 15;
  const int quad = lane >> 4;

  __shared__ __attribute__((aligned(16))) short Ahi[16 * 256];
  __shared__ __attribute__((aligned(16))) short Alo[16 * 256];
  __shared__ float g_lds[12 * GSTR];
  __shared__ float red[128];

  for (int i = t; i < 16 * 256 / 2; i += 512) {
    ((int*)Ahi)[i] = 0;
    ((int*)Alo)[i] = 0;
  }

  // persistent weight fragments: 6 n-tiles x 8 ks (K=256, h_row|h_col part of W)
  short8 w[6][8];
  {
    const float* wb = W_enc + (size_t)cls * 768 * 384;
#pragma unroll
    for (int n6 = 0; n6 < 6; ++n6)
#pragma unroll
      for (int ks = 0; ks < 8; ++ks)
        w[n6][ks] = ldfrag(wb, 384, (wv * 6 + n6) * 16, ks * 32, lane);
  }
  const __half* xg_base = xWb + ((size_t)cls * 64 + bn) * 192 * 768;
  __syncthreads();

  for (int s = 0; s < Steps; ++s) {
    // ---- GEMM: A(LDS, swizzled, hi/lo) x W(regs) ----
    f32x4 acc[6] = {{0.f, 0.f, 0.f, 0.f}, {0.f, 0.f, 0.f, 0.f}, {0.f, 0.f, 0.f, 0.f},
                    {0.f, 0.f, 0.f, 0.f}, {0.f, 0.f, 0.f, 0.f}, {0.f, 0.f, 0.f, 0.f}};
#pragma unroll
    for (int ks = 0; ks < 8; ++ks) {
      int ao = aidx(arow, ks * 32 + quad * 8);
      short8 ah = *(const short8*)&Ahi[ao];
      short8 al = *(const short8*)&Alo[ao];
#pragma unroll
      for (int n6 = 0; n6 < 6; ++n6) {
        acc[n6] = __builtin_amdgcn_mfma_f32_16x16x32_bf16(ah, w[n6][ks], acc[n6], 0, 0, 0);
        acc[n6] = __builtin_amdgcn_mfma_f32_16x16x32_bf16(al, w[n6][ks], acc[n6], 0, 0, 0);
      }
    }

    // ---- xWb gate loads for this step (LLC; latency hidden by spill+barrier) ----
    __half hx[3][6];
#pragma unroll
    for (int i = 0; i < 3; ++i) {
      int pos = t + i * 512;
      int c = pos >> 7, d = pos & 127;
      int r = s - c;
      if (r >= 0 && r < 16) {
        const __half* xp = xg_base + (size_t)(r * 12 + c) * 768 + d;
#pragma unroll
        for (int g6 = 0; g6 < 6; ++g6) hx[i][g6] = xp[g6 * 128];
      } else {
#pragma unroll
        for (int g6 = 0; g6 < 6; ++g6) hx[i][g6] = __float2half(0.f);
      }
    }

    // ---- spill D to g_lds ----
    if (quad < 3) {
      int c0 = wv * 96 + arow;
#pragma unroll
      for (int r = 0; r < 4; ++r) {
        int row = quad * 4 + r;
#pragma unroll
        for (int n6 = 0; n6 < 6; ++n6) g_lds[row * GSTR + c0 + n6 * 16] = acc[n6][r];
      }
    }
    __syncthreads();  // #1

    // ---- read old h (before overwrite; col-roll WAR) ----
    float hro[3], hco[3];
#pragma unroll
    for (int i = 0; i < 3; ++i) {
      int pos = t + i * 512;
      int c = pos >> 7, d = pos & 127;
      int ar = aidx(c, d), ac = aidx(c, 128 + d);
      hro[i] = bf2f(Ahi[ar]) + bf2f(Alo[ar]);
      hco[i] = bf2f(Ahi[ac]) + bf2f(Alo[ac]);
    }
    __syncthreads();  // #2

    // ---- gated update; write h_row and rolled h_col back into A ----
#pragma unroll
    for (int i = 0; i < 3; ++i) {
      int pos = t + i * 512;
      int c = pos >> 7, d = pos & 127;
      const float* gr = &g_lds[c * GSTR + d];
      float g0 = gr[0] + __half2float(hx[i][0]);
      float g1 = gr[128] + __half2float(hx[i][1]);
      float g2 = gr[256] + __half2float(hx[i][2]);
      float g3 = gr[384] + __half2float(hx[i][3]);
      float g4 = gr[512] + __half2float(hx[i][4]);
      float g5 = gr[640] + __half2float(hx[i][5]);
      float ur = sigmoidf_(g0), orr = sigmoidf_(g1);
      float uc = sigmoidf_(g2), oc = sigmoidf_(g3);
      float ir = tanh_(g4), ic = tanh_(g5);
      float hr = tanh_((1.f - ur) * hro[i] + ur * ir) * orr;
      float hc = tanh_((1.f - uc) * hco[i] + uc * ic) * oc;
      unsigned rp = packbf(hr), cp = packbf(hc);
      int ar = aidx(c, d);
      Ahi[ar] = (short)(rp >> 16);
      Alo[ar] = (short)(rp & 0xFFFFu);
      int c2 = (c == 11) ? 0 : c + 1;  // roll: new h_col[c] feeds slice c+1
      int ac = aidx(c2, 128 + d);
      Ahi[ac] = (short)(cp >> 16);
      Alo[ac] = (short)(cp & 0xFFFFu);
    }
    __syncthreads();  // #3
  }

  // ---- epilogue: h_row[11] at A[11][k=t]; h_col_new[11] at A[0][k=128+t] ----
  if (t < 128) {
    int ar = aidx(11, t), ac = aidx(0, 128 + t);
    float hr = bf2f(Ahi[ar]) + bf2f(Alo[ar]);
    float hc = bf2f(Ahi[ac]) + bf2f(Alo[ac]);
    red[t] = 0.5f * (hc * fc1_w[cls * Hdim + t] + hr * fc2_w[cls * Hdim + t]);
  }
  __syncthreads();
  if (t == 0) {
    float sum = 0.f;
    for (int i = 0; i < 128; ++i) sum += red[i];
    out[bn * 2 + cls] = sum + 0.5f * (fc1_b[cls] + fc2_b[cls]);
  }
}

extern "C" void kernel_launch(void* const* d_in, const int* in_sizes, int n_in,
                              void* d_out, int out_size, void* d_ws, size_t ws_size,
                              hipStream_t stream) {
  const float* x = (const float*)d_in[0];
  // d_in[1] = pad_mask: unused by the reference
  const float* fc3_w = (const float*)d_in[2];
  const float* fc3_b = (const float*)d_in[3];
  const float* fc4_w = (const float*)d_in[4];
  const float* fc4_b = (const float*)d_in[5];
  const float* W_enc = (const float*)d_in[6];
  const float* B_enc = (const float*)d_in[7];
  const float* fc1_w = (const float*)d_in[8];
  const float* fc1_b = (const float*)d_in[9];
  const float* fc2_w = (const float*)d_in[10];
  const float* fc2_b = (const float*)d_in[11];
  float* out = (float*)d_out;

  __half* xWb = (__half*)d_ws;  // 2 x 64 x 192 x 768 x 2 B = 37,748,736 B

  prelude<<<dim3(192), dim3(512), 0, stream>>>(x, fc3_w, fc3_b, fc4_w, fc4_b, W_enc, B_enc, xWb);
  witran<<<dim3(128), dim3(512), 0, stream>>>(W_enc, fc1_w, fc1_b, fc2_w, fc2_b, xWb, out);
}

// Round 6
// 210.546 us; speedup vs baseline: 1.8145x; 1.8145x over previous
//
#include <hip/hip_runtime.h>

typedef _Float16 hf;
typedef _Float16 half8 __attribute__((ext_vector_type(8)));
typedef float f32x4 __attribute__((ext_vector_type(4)));

constexpr int Steps = 27;
constexpr int GSTR = 772;  // g_lds row stride (floats)

// ws half-index layout (prep writes, others read):
//   wfrag16 : [0, 393216)        ((cls*48+nt)*8+ks)*512 + lane*8 + j   (K=0..256, recurrent)
//   wxf     : [393216, 655360)   (ptg*4+ks)*512 + lane*8 + j           (K=256..384, x part)
//   fc3f    : [655360, 663552)   (nt*2+ks)*512 + ...
//   fc4f    : [663552, 679936)   (nt*4+ks)*512 + ...
//   xWb     : [679936, +18874368) [cls][bn][l][n] fp16
constexpr int OFF_WX = 393216;
constexpr int OFF_F3 = 655360;
constexpr int OFF_F4 = 663552;
constexpr int OFF_XW = 679936;

__device__ __forceinline__ int aidx(int r, int k) {  // halfs, K=256 (witran A)
  int blk = k >> 3;
  return r * 256 + (((blk ^ (r & 7)) & 31) << 3) + (k & 7);
}
__device__ __forceinline__ int hidx(int r, int k) {  // halfs, K=128 (prelude h buffers)
  int blk = k >> 3;
  return r * 128 + (((blk ^ (r & 15)) & 15) << 3) + (k & 7);
}
__device__ __forceinline__ int xidx(int r, int k) {  // halfs, K=64 (prelude x)
  int blk = k >> 3;
  return r * 64 + (((blk ^ (r & 7)) & 7) << 3) + (k & 7);
}
__device__ __forceinline__ float sigmoidf_(float x) { return 1.0f / (1.0f + __expf(-x)); }
__device__ __forceinline__ float tanh_(float x) { return 1.0f - 2.0f / (__expf(2.0f * x) + 1.0f); }

// ---- kernel 1: all weights -> fragment-ordered fp16 (fully coalesced) ----
__global__ __launch_bounds__(512) void prep(const float* __restrict__ fc3_w,
                                            const float* __restrict__ fc4_w,
                                            const float* __restrict__ W_enc,
                                            hf* __restrict__ wsh) {
  int idx = blockIdx.x * 512 + threadIdx.x;
  float v;
  if (idx < OFF_WX) {                       // recurrent W, K in [0,256)
    int j = idx & 7, lane = (idx >> 3) & 63, rest = idx >> 9;
    int ks = rest & 7, tmp = rest >> 3, nt = tmp % 48, cls = tmp / 48;
    int n = nt * 16 + (lane & 15), k = ks * 32 + ((lane >> 4) << 3) + j;
    v = W_enc[(cls * 768 + n) * 384 + k];
  } else if (idx < OFF_F3) {                // x-part Wx, K in [256,384)
    int f = idx - OFF_WX;
    int j = f & 7, lane = (f >> 3) & 63, rest = f >> 9;
    int ks = rest & 3, ptg = rest >> 2;     // ptg in [0,96): cls*48+pt
    int n = (ptg % 48) * 16 + (lane & 15), k = 256 + ks * 32 + ((lane >> 4) << 3) + j;
    v = W_enc[((ptg / 48) * 768 + n) * 384 + k];
  } else if (idx < OFF_F4) {                // fc3
    int f = idx - OFF_F3;
    int j = f & 7, lane = (f >> 3) & 63, rest = f >> 9;
    int ks = rest & 1, nt = rest >> 1;
    int n = nt * 16 + (lane & 15), k = ks * 32 + ((lane >> 4) << 3) + j;
    v = fc3_w[n * 64 + k];
  } else if (idx < OFF_XW) {                // fc4
    int f = idx - OFF_F4;
    int j = f & 7, lane = (f >> 3) & 63, rest = f >> 9;
    int ks = rest & 3, nt = rest >> 2;
    int n = nt * 16 + (lane & 15), k = ks * 32 + ((lane >> 4) << 3) + j;
    v = fc4_w[n * 128 + k];
  } else {
    return;
  }
  wsh[idx] = (hf)v;
}

// ---- kernel 2: frontend MLP + xW precompute, all MFMA fp16, frags coalesced ----
__global__ __launch_bounds__(512) void prelude(
    const float* __restrict__ x, const float* __restrict__ fc3_b, const float* __restrict__ fc4_b,
    const float* __restrict__ B_enc, const hf* __restrict__ wsh, hf* __restrict__ xWb) {
  const int t = threadIdx.x, lane = t & 63, wv = t >> 6;
  const int c16 = lane & 15, quad = lane >> 4;
  const int row0 = blockIdx.x * 64, bn = row0 / 192, l0 = row0 % 192;

  __shared__ __attribute__((aligned(16))) hf xA[64 * 64];
  __shared__ __attribute__((aligned(16))) hf hbuf[64 * 128];
  __shared__ float actf[64];

  {  // stage x -> fp16 swizzled LDS
    int r = t >> 3, cb = (t & 7) * 8;
    const float* xp = x + (size_t)(row0 + r) * 64 + cb;
    f32x4 a = *(const f32x4*)xp, b = *(const f32x4*)(xp + 4);
    half8 h;
    h[0] = (hf)a.x; h[1] = (hf)a.y; h[2] = (hf)a.z; h[3] = (hf)a.w;
    h[4] = (hf)b.x; h[5] = (hf)b.y; h[6] = (hf)b.z; h[7] = (hf)b.w;
    *(half8*)&xA[xidx(r, cb)] = h;
  }
  if (t < 64) {
    int l = l0 + t;
    actf[t] = ((l / 12) + (l % 12)) < 12 ? 1.f : 0.f;
  }
  __syncthreads();

  // ---- fc3: relu(x @ w3^T + b3) -> hbuf ----
  {
    float b3v = fc3_b[wv * 16 + c16];
    half8 w0 = *(const half8*)(wsh + OFF_F3 + (wv * 2 + 0) * 512 + lane * 8);
    half8 w1 = *(const half8*)(wsh + OFF_F3 + (wv * 2 + 1) * 512 + lane * 8);
    f32x4 acc[4] = {{0, 0, 0, 0}, {0, 0, 0, 0}, {0, 0, 0, 0}, {0, 0, 0, 0}};
#pragma unroll
    for (int mt = 0; mt < 4; ++mt) {
      half8 a0 = *(const half8*)&xA[xidx(mt * 16 + c16, quad * 8)];
      half8 a1 = *(const half8*)&xA[xidx(mt * 16 + c16, 32 + quad * 8)];
      acc[mt] = __builtin_amdgcn_mfma_f32_16x16x32_f16(a0, w0, acc[mt], 0, 0, 0);
      acc[mt] = __builtin_amdgcn_mfma_f32_16x16x32_f16(a1, w1, acc[mt], 0, 0, 0);
    }
#pragma unroll
    for (int mt = 0; mt < 4; ++mt)
#pragma unroll
      for (int r = 0; r < 4; ++r)
        hbuf[hidx(mt * 16 + quad * 4 + r, wv * 16 + c16)] = (hf)fmaxf(acc[mt][r] + b3v, 0.f);
  }
  __syncthreads();

  // ---- fc4: h1 @ w4^T + b4 -> hg (overwrites hbuf after barrier) ----
  {
    float b4v = fc4_b[wv * 16 + c16];
    half8 w4[4];
#pragma unroll
    for (int ks = 0; ks < 4; ++ks)
      w4[ks] = *(const half8*)(wsh + OFF_F4 + (wv * 4 + ks) * 512 + lane * 8);
    f32x4 acc[4] = {{0, 0, 0, 0}, {0, 0, 0, 0}, {0, 0, 0, 0}, {0, 0, 0, 0}};
#pragma unroll
    for (int mt = 0; mt < 4; ++mt)
#pragma unroll
      for (int ks = 0; ks < 4; ++ks) {
        half8 a = *(const half8*)&hbuf[hidx(mt * 16 + c16, ks * 32 + quad * 8)];
        acc[mt] = __builtin_amdgcn_mfma_f32_16x16x32_f16(a, w4[ks], acc[mt], 0, 0, 0);
      }
    __syncthreads();  // all h1 reads done before overwrite
#pragma unroll
    for (int mt = 0; mt < 4; ++mt)
#pragma unroll
      for (int r = 0; r < 4; ++r)
        hbuf[hidx(mt * 16 + quad * 4 + r, wv * 16 + c16)] = (hf)(acc[mt][r] + b4v);
  }
  __syncthreads();

  // ---- xW: hg @ Wx^T (+ masked bias) -> xWb fp16. A-frags hoisted, Wx streamed once ----
  {
    half8 af[4][4];
#pragma unroll
    for (int mt = 0; mt < 4; ++mt)
#pragma unroll
      for (int ks = 0; ks < 4; ++ks)
        af[mt][ks] = *(const half8*)&hbuf[hidx(mt * 16 + c16, ks * 32 + quad * 8)];
    for (int i = 0; i < 12; ++i) {
      int ptg = wv * 12 + i;            // 0..95
      int cls = ptg / 48, pt = ptg % 48;
      half8 wf[4];
#pragma unroll
      for (int ks = 0; ks < 4; ++ks)
        wf[ks] = *(const half8*)(wsh + OFF_WX + (ptg * 4 + ks) * 512 + lane * 8);
      float bv = B_enc[cls * 768 + pt * 16 + c16];
      hf* dst = xWb + (((size_t)cls * 64 + bn) * 192 + l0) * 768 + pt * 16 + c16;
#pragma unroll
      for (int mt = 0; mt < 4; ++mt) {
        f32x4 acc = {0.f, 0.f, 0.f, 0.f};
#pragma unroll
        for (int ks = 0; ks < 4; ++ks)
          acc = __builtin_amdgcn_mfma_f32_16x16x32_f16(af[mt][ks], wf[ks], acc, 0, 0, 0);
#pragma unroll
        for (int r = 0; r < 4; ++r) {
          int row = mt * 16 + quad * 4 + r;
          dst[(size_t)row * 768] = (hf)(acc[r] + actf[row] * bv);
        }
      }
    }
  }
}

// ---- kernel 3: recurrence, 1 wg per (cls,bn), fp16 GEMM, weights register-resident ----
__global__ __launch_bounds__(512) __attribute__((amdgpu_waves_per_eu(2, 2))) void witran(
    const hf* __restrict__ wsh, const float* __restrict__ fc1_w, const float* __restrict__ fc1_b,
    const float* __restrict__ fc2_w, const float* __restrict__ fc2_b,
    const hf* __restrict__ xWb, float* __restrict__ out) {
  const int cls = blockIdx.x & 1, bn = blockIdx.x >> 1;
  const int t = threadIdx.x, lane = t & 63, wv = t >> 6;
  const int c16 = lane & 15, quad = lane >> 4;

  __shared__ __attribute__((aligned(16))) hf A[16 * 256];
  __shared__ float g_lds[12 * GSTR];
  __shared__ float red[128];

  for (int i = t; i < 2048; i += 512) ((int*)A)[i] = 0;

  // 48 register-resident fp16 W fragments: wave wv owns n-cols [wv*96, wv*96+96)
  half8 w[6][8];
#pragma unroll
  for (int n6 = 0; n6 < 6; ++n6)
#pragma unroll
    for (int ks = 0; ks < 8; ++ks)
      w[n6][ks] = *(const half8*)(wsh + ((cls * 48 + wv * 6 + n6) * 8 + ks) * 512 + lane * 8);

  const hf* xg = xWb + ((size_t)cls * 64 + bn) * 192 * 768;
  __syncthreads();

  for (int s = 0; s < Steps; ++s) {
    // ---- prefetch this step's xW gates (consumed after barrier #1) ----
    hf xv[3][6];
#pragma unroll
    for (int i = 0; i < 3; ++i) {
      int pos = t + i * 512;
      int c = pos >> 7, d = pos & 127;
      int r = s - c;
      if (r >= 0 && r < 16) {
        const hf* xp = xg + (size_t)(r * 12 + c) * 768 + d;
#pragma unroll
        for (int g6 = 0; g6 < 6; ++g6) xv[i][g6] = xp[g6 * 128];
      } else {
#pragma unroll
        for (int g6 = 0; g6 < 6; ++g6) xv[i][g6] = (hf)0.f;
      }
    }

    // ---- GEMM: A (LDS fp16, swizzled) x W (regs), K=256 ----
    f32x4 acc[6] = {{0, 0, 0, 0}, {0, 0, 0, 0}, {0, 0, 0, 0},
                    {0, 0, 0, 0}, {0, 0, 0, 0}, {0, 0, 0, 0}};
#pragma unroll
    for (int ks = 0; ks < 8; ++ks) {
      half8 a = *(const half8*)&A[aidx(c16, ks * 32 + quad * 8)];
#pragma unroll
      for (int n6 = 0; n6 < 6; ++n6)
        acc[n6] = __builtin_amdgcn_mfma_f32_16x16x32_f16(a, w[n6][ks], acc[n6], 0, 0, 0);
    }

    // ---- spill D to g_lds (natural n-order) ----
    if (quad < 3) {
#pragma unroll
      for (int r = 0; r < 4; ++r) {
        int base = (quad * 4 + r) * GSTR + wv * 96 + c16;
#pragma unroll
        for (int n6 = 0; n6 < 6; ++n6) g_lds[base + n6 * 16] = acc[n6][r];
      }
    }

    // ---- read old h before anyone overwrites (A-reads all precede barrier #1) ----
    float hro[3], hco[3];
#pragma unroll
    for (int i = 0; i < 3; ++i) {
      int pos = t + i * 512;
      int c = pos >> 7, d = pos & 127;
      hro[i] = (float)A[aidx(c, d)];
      hco[i] = (float)A[aidx(c, 128 + d)];
    }
    __syncthreads();  // #1: spills visible; all A reads done

    // ---- gated update; write h_row and rolled h_col into A ----
#pragma unroll
    for (int i = 0; i < 3; ++i) {
      int pos = t + i * 512;
      int c = pos >> 7, d = pos & 127;
      const float* gr = &g_lds[c * GSTR + d];
      float g0 = gr[0] + (float)xv[i][0];
      float g1 = gr[128] + (float)xv[i][1];
      float g2 = gr[256] + (float)xv[i][2];
      float g3 = gr[384] + (float)xv[i][3];
      float g4 = gr[512] + (float)xv[i][4];
      float g5 = gr[640] + (float)xv[i][5];
      float ur = sigmoidf_(g0), orr = sigmoidf_(g1);
      float uc = sigmoidf_(g2), oc = sigmoidf_(g3);
      float ir = tanh_(g4), ic = tanh_(g5);
      float hr = tanh_((1.f - ur) * hro[i] + ur * ir) * orr;
      float hc = tanh_((1.f - uc) * hco[i] + uc * ic) * oc;
      A[aidx(c, d)] = (hf)hr;
      int c2 = (c == 11) ? 0 : c + 1;  // roll: new h_col[c] feeds slice c+1
      A[aidx(c2, 128 + d)] = (hf)hc;
    }
    __syncthreads();  // #2: A complete for next step
  }

  // ---- epilogue: h_row[11] at A[11][0:128); rolled h_col[11] at A[0][128:256) ----
  if (t < 128) {
    float hr = (float)A[aidx(11, t)];
    float hc = (float)A[aidx(0, 128 + t)];
    red[t] = 0.5f * (hc * fc1_w[cls * 128 + t] + hr * fc2_w[cls * 128 + t]);
  }
  __syncthreads();
  if (t == 0) {
    float sum = 0.f;
    for (int i = 0; i < 128; ++i) sum += red[i];
    out[bn * 2 + cls] = sum + 0.5f * (fc1_b[cls] + fc2_b[cls]);
  }
}

extern "C" void kernel_launch(void* const* d_in, const int* in_sizes, int n_in,
                              void* d_out, int out_size, void* d_ws, size_t ws_size,
                              hipStream_t stream) {
  const float* x = (const float*)d_in[0];
  // d_in[1] = pad_mask: unused by the reference
  const float* fc3_w = (const float*)d_in[2];
  const float* fc3_b = (const float*)d_in[3];
  const float* fc4_w = (const float*)d_in[4];
  const float* fc4_b = (const float*)d_in[5];
  const float* W_enc = (const float*)d_in[6];
  const float* B_enc = (const float*)d_in[7];
  const float* fc1_w = (const float*)d_in[8];
  const float* fc1_b = (const float*)d_in[9];
  const float* fc2_w = (const float*)d_in[10];
  const float* fc2_b = (const float*)d_in[11];
  float* out = (float*)d_out;

  hf* wsh = (hf*)d_ws;             // frag tables: 1,359,872 B
  hf* xWb = wsh + OFF_XW;          // 37,748,736 B -> total 39,108,608 B

  prep<<<dim3(1328), dim3(512), 0, stream>>>(fc3_w, fc4_w, W_enc, wsh);
  prelude<<<dim3(192), dim3(512), 0, stream>>>(x, fc3_b, fc4_b, B_enc, wsh, xWb);
  witran<<<dim3(128), dim3(512), 0, stream>>>(wsh, fc1_w, fc1_b, fc2_w, fc2_b, xWb, out);
}